// Round 1
// baseline (99.071 us; speedup 1.0000x reference)
//
#include <hip/hip_runtime.h>
#include <hip/hip_bf16.h>

// KPConv fused kernel for MI355X (gfx950).
// B=4, M=16384, K_NB=32, D_IN=64, D_OUT=64, K_PTS=15, SIGMA=1.
//
// Stage 1 (per point): h[k][p] = max(0, 1-|r_k - Q_p|), Fk[p][d] = sum_k h[k][p]*Fn[k][d]
//   -> one mfma_f32_16x16x32_bf16 per 16-wide d-tile (A = h^T [16p x 32k], B = Fn [32k x 16d])
// Stage 2 (per 16-point tile): out[m][e] = sum_{pd} Fk[m][pd] * W[pd][e]
//   -> K=960 = 30 k-steps of mfma_f32_16x16x32_bf16; W B-fragments pre-built in ws (bf16),
//      held in 120 VGPRs per wave (one e-tile per wave).

#define BATCH 4
#define MPTS  16384
#define KNB   32
#define DIN   64
#define DOUT  64
#define KP    15
#define K2    (KP*DIN)      // 960
#define KSTEPS (K2/32)      // 30
#define ROWBYTES (K2*2)     // 1920 bytes per Fk row (bf16)
#define PTS   (BATCH*MPTS)  // 65536

typedef __bf16 bf16x8 __attribute__((ext_vector_type(8)));
typedef float  f32x4  __attribute__((ext_vector_type(4)));

static __device__ __forceinline__ unsigned short f2b(float x) {
    __bf16 h = (__bf16)x;              // RNE convert
    return __builtin_bit_cast(unsigned short, h);
}

// ---- prep: W [15][64][64] f32 -> bf16 B-fragments in ws ----
// layout: wb[ ((etile*KSTEPS + kstep)*64 + lane)*8 + i ]
//   holds W[k = kstep*32 + (lane>>4)*8 + i][e = etile*16 + (lane&15)]
__global__ void prep_wb(const float* __restrict__ W, unsigned short* __restrict__ wb) {
    int idx = blockIdx.x * 256 + threadIdx.x;
    if (idx >= KP * DIN * DOUT) return;
    int i    = idx & 7;
    int lane = (idx >> 3) & 63;
    int ks   = (idx >> 9) % KSTEPS;
    int et   = idx / (KSTEPS * 512);
    int k = ks * 32 + (lane >> 4) * 8 + i;
    int p = k >> 6;
    int d = k & 63;
    int e = et * 16 + (lane & 15);
    wb[idx] = f2b(W[(p * DIN + d) * DOUT + e]);
}

__global__ __launch_bounds__(256, 2)
void kpconv_main(const float* __restrict__ X, const float* __restrict__ F,
                 const int* __restrict__ NB, const float* __restrict__ Q,
                 const unsigned short* __restrict__ WB, float* __restrict__ OUT) {
    __shared__ float4 r4s[4][KNB];            // per-wave: (rx,ry,rz,|r|^2)
    __shared__ int    idxs[4][KNB];           // per-wave: global F row of neighbor
    __shared__ unsigned short fk[16 * K2];    // 16 Fk rows, bf16, XOR-swizzled 16B chunks

    const int tid  = threadIdx.x;
    const int wv   = tid >> 6;    // wave 0..3 = e-tile
    const int lane = tid & 63;
    const int g16  = lane >> 4;   // 0..3
    const int r16  = lane & 15;   // 0..15

    // W B-fragments for this wave's e-tile: 30 x 16B = 120 VGPRs, resident all kernel
    bf16x8 bw[KSTEPS];
    {
        const unsigned short* base = WB + ((size_t)(wv * KSTEPS) * 64 + lane) * 8;
        #pragma unroll
        for (int ks = 0; ks < KSTEPS; ++ks)
            bw[ks] = *reinterpret_cast<const bf16x8*>(base + ks * 512);
    }

    // per-lane kernel-point constants (stage-1 A row p = r16; p=15 is the zero pad row)
    float q2x = 0.f, q2y = 0.f, q2z = 0.f, qq = 0.f;
    const bool pvalid = (r16 < KP);
    if (pvalid) {
        float qx = Q[r16 * 3 + 0], qy = Q[r16 * 3 + 1], qz = Q[r16 * 3 + 2];
        q2x = 2.f * qx; q2y = 2.f * qy; q2z = 2.f * qz;
        qq = qx * qx + qy * qy + qz * qz;
    }

    for (int tile = 0; tile < 8; ++tile) {
        const int tile_pid = blockIdx.x * 128 + tile * 16;

        // ---------------- stage 1: 4 points per wave ----------------
        for (int j = 0; j < 4; ++j) {
            const int row = wv * 4 + j;          // Fk row within tile
            const int pid = tile_pid + row;      // global point id
            const int b   = pid >> 14;
            // stage r-vectors + neighbor rows (lanes 0..31); same-wave LDS is in-order
            if (lane < KNB) {
                int nb = NB[(size_t)pid * KNB + lane];
                const float* xn = X + (size_t)(b * MPTS + nb) * 3;
                const float* xc = X + (size_t)pid * 3;
                float rx = xn[0] - xc[0];
                float ry = xn[1] - xc[1];
                float rz = xn[2] - xc[2];
                r4s[wv][lane]  = make_float4(rx, ry, rz, rx * rx + ry * ry + rz * rz);
                idxs[wv][lane] = b * MPTS + nb;
            }

            // A fragment: h for p=r16, neighbors k = g16*8 + i
            bf16x8 ah;
            #pragma unroll
            for (int i = 0; i < 8; ++i) {
                float4 rv = r4s[wv][g16 * 8 + i];
                float d2 = rv.w + qq - q2x * rv.x - q2y * rv.y - q2z * rv.z;
                d2 = fmaxf(d2, 0.f);
                float h = 1.f - sqrtf(d2);
                h = (pvalid && h > 0.f) ? h : 0.f;
                ah[i] = (__bf16)h;
            }

            // neighbor rows (hoisted, uniform per 16-lane group)
            int nbs[8];
            #pragma unroll
            for (int i = 0; i < 8; ++i) nbs[i] = idxs[wv][g16 * 8 + i];

            // B fragments (gathered Fn columns) + 4 MFMAs
            f32x4 acc[4];
            #pragma unroll
            for (int t = 0; t < 4; ++t) {
                bf16x8 bf;
                #pragma unroll
                for (int i = 0; i < 8; ++i) {
                    float v = F[(size_t)nbs[i] * DIN + t * 16 + r16];
                    bf[i] = (__bf16)v;
                }
                f32x4 zero = {0.f, 0.f, 0.f, 0.f};
                acc[t] = __builtin_amdgcn_mfma_f32_16x16x32_bf16(ah, bf, zero, 0, 0, 0);
            }

            // write Fk row to LDS (bf16), XOR-swizzle on 16B chunks within the row
            #pragma unroll
            for (int t = 0; t < 4; ++t) {
                #pragma unroll
                for (int r = 0; r < 4; ++r) {
                    int p = g16 * 4 + r;         // D row = kernel point
                    if (p < KP) {
                        int pd    = p * DIN + t * 16 + r16;
                        int chunk = (pd >> 3) ^ (row & 7);
                        int off   = row * ROWBYTES + chunk * 16 + (pd & 7) * 2;
                        *reinterpret_cast<unsigned short*>(
                            reinterpret_cast<char*>(fk) + off) = f2b(acc[t][r]);
                    }
                }
            }
        }

        __syncthreads();   // all 16 Fk rows visible to all waves

        // ---------------- stage 2: [16 x 960] x [960 x 16] per wave ----------------
        f32x4 o = {0.f, 0.f, 0.f, 0.f};
        #pragma unroll
        for (int ks = 0; ks < KSTEPS; ++ks) {
            int chunk = (ks * 4 + g16) ^ (r16 & 7);
            bf16x8 a = *reinterpret_cast<const bf16x8*>(
                reinterpret_cast<const char*>(fk) + r16 * ROWBYTES + chunk * 16);
            o = __builtin_amdgcn_mfma_f32_16x16x32_bf16(a, bw[ks], o, 0, 0, 0);
        }

        #pragma unroll
        for (int r = 0; r < 4; ++r) {
            int prow = g16 * 4 + r;                  // D row = point within tile
            int pid  = tile_pid + prow;
            OUT[(size_t)pid * DOUT + wv * 16 + r16] = o[r];
        }

        __syncthreads();   // protect fk before next tile overwrites it
    }
}

extern "C" void kernel_launch(void* const* d_in, const int* in_sizes, int n_in,
                              void* d_out, int out_size, void* d_ws, size_t ws_size,
                              hipStream_t stream) {
    const float* X = (const float*)d_in[0];
    const float* F = (const float*)d_in[1];
    const int*   N = (const int*)d_in[2];
    const float* Q = (const float*)d_in[3];
    const float* W = (const float*)d_in[4];
    float* OUT = (float*)d_out;
    unsigned short* WB = (unsigned short*)d_ws;   // 61440 * 2 B = 120 KiB

    prep_wb<<<(KP * DIN * DOUT + 255) / 256, 256, 0, stream>>>(W, WB);
    kpconv_main<<<PTS / 128, 256, 0, stream>>>(X, F, N, Q, WB, OUT);
}